// Round 2
// baseline (114.631 us; speedup 1.0000x reference)
//
#include <hip/hip_runtime.h>

// STAttn fused: B,T,N,D = 32,32,64,512; H=64; OUT=256
// One block per bt-group (1024 blocks, 256 threads = 4 waves).
// Phase 1: h = lrelu(x@ue_w^T + ue_b + be)  [64n x 64h GEMM, K=512]
// Phase 2: e = h@w_w  (w_b dropped: softmax shift-invariant); a = softmax_N(e)
// Phase 3: attr[d] = sum_n a[n] x[n][d]  -> LDS
// Phase 4: out[t*32+b][o] = attr @ fc1_w[o]^T + fc1_b[o]
// No d_ws use (R1 post-timing divergence was consistent with d_ws OOB corrupting d_in).

#define D_DIM 512
#define N_TOK 64
#define BK    32
#define XSTR  20   // 16 tokens + 4 pad (transposed X tile stride)
#define WSTR  68   // 64 rows + 4 pad (transposed W tile stride)

__global__ __launch_bounds__(256, 4) void stattn_fused(
    const float* __restrict__ inp,    // [1024][64][512]
    const float* __restrict__ ue_w,   // [64][512]
    const float* __restrict__ ue_b,   // [64]
    const float* __restrict__ be,     // [64]
    const float* __restrict__ w_w,    // [64]
    const float* __restrict__ fc1_w,  // [256][512]
    const float* __restrict__ fc1_b,  // [256]
    float* __restrict__ out)          // [1024][256], row = (bt&31)*32 + (bt>>5)
{
    __shared__ float WsT[BK * WSTR];     // transposed ue_w tile [k][j]
    __shared__ float XsT[4][BK * XSTR];  // per-wave transposed X tile [k][n_loc]
    __shared__ float e_s[N_TOK];
    __shared__ float a_s[N_TOK];
    __shared__ float attr_s[D_DIM];

    const int tid  = threadIdx.x;
    const int wv   = tid >> 6;        // wave 0..3: owns tokens [wv*16, wv*16+16)
    const int lane = tid & 63;
    const int rx   = lane & 7;        // j-group (8 j each)
    const int ry   = lane >> 3;       // n-pair (2 n each)
    const int bt   = blockIdx.x;
    const float* __restrict__ xbase = inp + (size_t)bt * (N_TOK * D_DIM);

    float acc[2][8];
#pragma unroll
    for (int i = 0; i < 2; ++i)
#pragma unroll
        for (int j = 0; j < 8; ++j) acc[i][j] = 0.f;

    float* __restrict__ xs = XsT[wv];

    // ---- Phase 1: h-GEMM (64 tokens x 64 hidden, K=512), wave owns 16 tokens
    for (int kt = 0; kt < D_DIM / BK; ++kt) {
        const int k0 = kt * BK;
        __syncthreads();  // previous iteration's readers done before overwrite
        // stage ue_w tile (64j x 32k -> transposed), 2 float4 per thread
#pragma unroll
        for (int i = 0; i < 2; ++i) {
            const int f  = tid + i * 256;
            const int j  = f >> 3;
            const int dk = (f & 7) << 2;
            const float4 v = *reinterpret_cast<const float4*>(&ue_w[j * D_DIM + k0 + dk]);
            WsT[(dk + 0) * WSTR + j] = v.x;
            WsT[(dk + 1) * WSTR + j] = v.y;
            WsT[(dk + 2) * WSTR + j] = v.z;
            WsT[(dk + 3) * WSTR + j] = v.w;
        }
        // stage this wave's 16-token X tile (16n x 32k -> transposed), 2 float4/lane
#pragma unroll
        for (int i = 0; i < 2; ++i) {
            const int f  = lane + i * 64;
            const int nl = f >> 3;
            const int dk = (f & 7) << 2;
            const int n  = wv * 16 + nl;
            const float4 v = *reinterpret_cast<const float4*>(&xbase[n * D_DIM + k0 + dk]);
            xs[(dk + 0) * XSTR + nl] = v.x;
            xs[(dk + 1) * XSTR + nl] = v.y;
            xs[(dk + 2) * XSTR + nl] = v.z;
            xs[(dk + 3) * XSTR + nl] = v.w;
        }
        __syncthreads();
#pragma unroll 8
        for (int k = 0; k < BK; ++k) {
            const float2 a2 = *reinterpret_cast<const float2*>(&xs[k * XSTR + ry * 2]);
            const float4 b0 = *reinterpret_cast<const float4*>(&WsT[k * WSTR + rx * 8]);
            const float4 b1 = *reinterpret_cast<const float4*>(&WsT[k * WSTR + rx * 8 + 4]);
            const float av[2] = {a2.x, a2.y};
            const float bv[8] = {b0.x, b0.y, b0.z, b0.w, b1.x, b1.y, b1.z, b1.w};
#pragma unroll
            for (int i = 0; i < 2; ++i)
#pragma unroll
                for (int j = 0; j < 8; ++j)
                    acc[i][j] = fmaf(av[i], bv[j], acc[i][j]);
        }
    }

    // ---- Phase 2: bias + leaky_relu + dot w_w -> e[n]; softmax over N
    {
        const int jb = rx * 8;
        const float4 ub0 = *reinterpret_cast<const float4*>(&ue_b[jb]);
        const float4 ub1 = *reinterpret_cast<const float4*>(&ue_b[jb + 4]);
        const float4 bb0 = *reinterpret_cast<const float4*>(&be[jb]);
        const float4 bb1 = *reinterpret_cast<const float4*>(&be[jb + 4]);
        const float4 ww0 = *reinterpret_cast<const float4*>(&w_w[jb]);
        const float4 ww1 = *reinterpret_cast<const float4*>(&w_w[jb + 4]);
        const float bias[8] = {ub0.x + bb0.x, ub0.y + bb0.y, ub0.z + bb0.z, ub0.w + bb0.w,
                               ub1.x + bb1.x, ub1.y + bb1.y, ub1.z + bb1.z, ub1.w + bb1.w};
        const float wwv[8]  = {ww0.x, ww0.y, ww0.z, ww0.w, ww1.x, ww1.y, ww1.z, ww1.w};
#pragma unroll
        for (int i = 0; i < 2; ++i) {
            float p = 0.f;
#pragma unroll
            for (int j = 0; j < 8; ++j) {
                float hv = acc[i][j] + bias[j];
                hv = hv > 0.f ? hv : 0.2f * hv;
                p = fmaf(hv, wwv[j], p);
            }
            p += __shfl_xor(p, 1);
            p += __shfl_xor(p, 2);
            p += __shfl_xor(p, 4);
            if (rx == 0) e_s[wv * 16 + ry * 2 + i] = p;
        }
    }
    __syncthreads();

    // softmax over 64 tokens (all waves compute; wave 0 writes)
    {
        const float v  = e_s[lane];
        float mx = v;
#pragma unroll
        for (int off = 32; off >= 1; off >>= 1) mx = fmaxf(mx, __shfl_xor(mx, off));
        const float ex = expf(v - mx);
        float sm = ex;
#pragma unroll
        for (int off = 32; off >= 1; off >>= 1) sm += __shfl_xor(sm, off);
        if (wv == 0) a_s[lane] = ex / sm;
    }
    __syncthreads();

    // ---- Phase 3: weighted pooling, wave covers 128 d's (float2 per lane)
    {
        const int d0 = wv * 128 + lane * 2;
        float ax = 0.f, ay = 0.f;
#pragma unroll 4
        for (int n = 0; n < N_TOK; ++n) {
            const float an  = a_s[n];
            const float2 xv = *reinterpret_cast<const float2*>(&xbase[n * D_DIM + d0]);
            ax = fmaf(an, xv.x, ax);
            ay = fmaf(an, xv.y, ay);
        }
        float2 o;
        o.x = ax; o.y = ay;
        *reinterpret_cast<float2*>(&attr_s[d0]) = o;
    }
    __syncthreads();

    // ---- Phase 4: fc — thread tid owns output o = tid
    {
        const int o = tid;
        const float* __restrict__ wrow = fc1_w + o * D_DIM;
        float s0 = 0.f, s1 = 0.f, s2 = 0.f, s3 = 0.f;
#pragma unroll 4
        for (int d0 = 0; d0 < D_DIM; d0 += 4) {
            const float4 a4 = *reinterpret_cast<const float4*>(&attr_s[d0]);
            const float4 w4 = *reinterpret_cast<const float4*>(&wrow[d0]);
            s0 = fmaf(a4.x, w4.x, s0);
            s1 = fmaf(a4.y, w4.y, s1);
            s2 = fmaf(a4.z, w4.z, s2);
            s3 = fmaf(a4.w, w4.w, s3);
        }
        const int row = (bt & 31) * 32 + (bt >> 5);  // out[t][b][o], b=bt>>5, t=bt&31
        out[row * 256 + o] = (s0 + s1) + (s2 + s3) + fc1_b[o];
    }
}

extern "C" void kernel_launch(void* const* d_in, const int* in_sizes, int n_in,
                              void* d_out, int out_size, void* d_ws, size_t ws_size,
                              hipStream_t stream) {
    const float* inp   = (const float*)d_in[0];
    const float* ue_w  = (const float*)d_in[1];
    const float* ue_b  = (const float*)d_in[2];
    const float* be    = (const float*)d_in[3];
    const float* w_w   = (const float*)d_in[4];
    // d_in[5] = w_b: unused (softmax invariant to constant shift of e)
    const float* fc1_w = (const float*)d_in[6];
    const float* fc1_b = (const float*)d_in[7];
    float* out = (float*)d_out;

    stattn_fused<<<1024, 256, 0, stream>>>(inp, ue_w, ue_b, be, w_w, fc1_w, fc1_b, out);
}

// Round 3
// 104.141 us; speedup vs baseline: 1.1007x; 1.1007x over previous
//
#include <hip/hip_runtime.h>

// STAttn fused, MFMA bf16x2-split version.
// B,T,N,D = 32,32,64,512; H=64; OUT=256.
// Grid: 512 blocks x 512 threads (8 waves). Block handles G=2 bt-groups.
// Phase 1: h = x @ ue_w^T via mfma_f32_32x32x16_bf16, operands direct from
//          global (no LDS, no barriers). wave = (g, token-half, hidden-half).
// Phase 2: e = lrelu(h+bias) @ w_w, cross-wave partial sum in LDS; softmax.
// Phase 3: pooling attr = sum_n a_n x_n, x re-read from global (L3-resident).
// Phase 4: fc = attr @ fc1_w^T via mfma_f32_16x16x32_bf16 (A rows 0..1 = groups).
// bf16x2 split (hi + lo residual, 3 MFMAs) keeps fp32-grade accuracy.

typedef __attribute__((ext_vector_type(8)))  short bf16x8;
typedef __attribute__((ext_vector_type(4)))  float f32x4;
typedef __attribute__((ext_vector_type(16))) float f32x16;

__device__ __forceinline__ unsigned short f2bf(float x) {
    unsigned u = __float_as_uint(x);
    u += 0x7FFFu + ((u >> 16) & 1u);   // round-to-nearest-even
    return (unsigned short)(u >> 16);
}

__device__ __forceinline__ void split8(const float* __restrict__ v,
                                       bf16x8& hi, bf16x8& lo) {
#pragma unroll
    for (int i = 0; i < 8; ++i) {
        unsigned short h = f2bf(v[i]);
        hi[i] = (short)h;
        float hf = __uint_as_float((unsigned)h << 16);
        lo[i] = (short)f2bf(v[i] - hf);
    }
}

__global__ __launch_bounds__(512, 4) void stattn_all(
    const float* __restrict__ inp,    // [1024][64][512]
    const float* __restrict__ ue_w,   // [64][512]
    const float* __restrict__ ue_b,   // [64]
    const float* __restrict__ be,     // [64]
    const float* __restrict__ w_w,    // [64]
    const float* __restrict__ fc1_w,  // [256][512]
    const float* __restrict__ fc1_b,  // [256]
    float* __restrict__ out)          // [1024][256]
{
    __shared__ __align__(16) float attr_s[2][512];
    __shared__ float ep_s[2][2][64];   // [g][jh][n] partial e
    __shared__ float a_s[2][64];

    const int tid = threadIdx.x;
    const int wv  = tid >> 6;
    const int l   = tid & 63;
    const int g   = wv >> 2;         // bt group within block
    const int nh  = (wv >> 1) & 1;   // token half  (32 tokens)
    const int jh  = wv & 1;          // hidden half (32 j)
    const int l31 = l & 31;
    const int kq  = (l >> 5) * 8;    // k sub-offset within a 16-wide K step

    const long bt = (long)blockIdx.x * 2 + g;
    const float* __restrict__ xg = inp + bt * (64 * 512);

    // ---------------- Phase 1: h-GEMM (32x32 tile per wave, K=512) ----------
    const float* __restrict__ arow = xg   + (nh * 32 + l31) * 512 + kq;
    const float* __restrict__ brow = ue_w + (jh * 32 + l31) * 512 + kq;

    f32x16 acc = {};
#pragma unroll 4
    for (int ks = 0; ks < 32; ++ks) {
        const int k = ks * 16;
        float av[8], bv[8];
        *reinterpret_cast<float4*>(&av[0]) = *reinterpret_cast<const float4*>(&arow[k]);
        *reinterpret_cast<float4*>(&av[4]) = *reinterpret_cast<const float4*>(&arow[k + 4]);
        *reinterpret_cast<float4*>(&bv[0]) = *reinterpret_cast<const float4*>(&brow[k]);
        *reinterpret_cast<float4*>(&bv[4]) = *reinterpret_cast<const float4*>(&brow[k + 4]);
        bf16x8 ahi, alo, bhi, blo;
        split8(av, ahi, alo);
        split8(bv, bhi, blo);
        acc = __builtin_amdgcn_mfma_f32_32x32x16_bf16(ahi, bhi, acc, 0, 0, 0);
        acc = __builtin_amdgcn_mfma_f32_32x32x16_bf16(alo, bhi, acc, 0, 0, 0);
        acc = __builtin_amdgcn_mfma_f32_32x32x16_bf16(ahi, blo, acc, 0, 0, 0);
    }

    // ---------------- Phase 2: e partials + softmax --------------------------
    // C/D layout (m74/m101): col j = l&31, row n_loc = (r&3) + 8*(r>>2) + 4*(l>>5)
    {
        const int j     = jh * 32 + l31;
        const float bias = ue_b[j] + be[j];
        const float ww   = w_w[j];
        float ep[16];
#pragma unroll
        for (int r = 0; r < 16; ++r) {
            float hv = acc[r] + bias;
            hv = hv > 0.f ? hv : 0.2f * hv;
            float p = hv * ww;
            p += __shfl_xor(p, 1);
            p += __shfl_xor(p, 2);
            p += __shfl_xor(p, 4);
            p += __shfl_xor(p, 8);
            p += __shfl_xor(p, 16);
            ep[r] = p;
        }
        if (l31 == 0) {
            const int hi = l >> 5;
#pragma unroll
            for (int r = 0; r < 16; ++r) {
                const int nr = (r & 3) + 8 * (r >> 2) + 4 * hi;
                ep_s[g][jh][nh * 32 + nr] = ep[r];
            }
        }
    }
    __syncthreads();

    // softmax over 64 tokens (per group; all waves compute, one writes)
    {
        float v  = ep_s[g][0][l] + ep_s[g][1][l];
        float mx = v;
#pragma unroll
        for (int off = 32; off >= 1; off >>= 1) mx = fmaxf(mx, __shfl_xor(mx, off));
        float ex = expf(v - mx);
        float sm = ex;
#pragma unroll
        for (int off = 32; off >= 1; off >>= 1) sm += __shfl_xor(sm, off);
        if ((wv & 3) == 0) a_s[g][l] = ex / sm;
    }
    __syncthreads();

    // ---------------- Phase 3: pooling (x from global, L3-resident) ---------
    {
        const int d0 = (nh * 2 + jh) * 128 + l * 2;
        const float* __restrict__ xp = xg + d0;
        float ax = 0.f, ay = 0.f;
#pragma unroll 8
        for (int n = 0; n < 64; ++n) {
            const float an = a_s[g][n];
            const float2 xv = *reinterpret_cast<const float2*>(&xp[n * 512]);
            ax = fmaf(an, xv.x, ax);
            ay = fmaf(an, xv.y, ay);
        }
        attr_s[g][d0]     = ax;
        attr_s[g][d0 + 1] = ay;
    }
    __syncthreads();

    // ---------------- Phase 4: fc GEMM (16x16x32, rows 0..1 = groups) -------
    {
        const int obase = wv * 32;
        const int q = l >> 4;     // k quad
        const int c = l & 15;     // column within tile / A-row
        const float* __restrict__ b0row = fc1_w + (size_t)(obase + c) * 512 + q * 8;
        const float* __restrict__ b1row = b0row + 16 * 512;
        f32x4 fa0 = {}, fa1 = {};
#pragma unroll 4
        for (int ks = 0; ks < 16; ++ks) {
            const int k = ks * 32;
            bf16x8 ahi = {}, alo = {};
            if (c < 2) {
                float av[8];
                *reinterpret_cast<float4*>(&av[0]) =
                    *reinterpret_cast<const float4*>(&attr_s[c][k + q * 8]);
                *reinterpret_cast<float4*>(&av[4]) =
                    *reinterpret_cast<const float4*>(&attr_s[c][k + q * 8 + 4]);
                split8(av, ahi, alo);
            }
            float bv[8];
            bf16x8 bhi, blo;
            *reinterpret_cast<float4*>(&bv[0]) = *reinterpret_cast<const float4*>(&b0row[k]);
            *reinterpret_cast<float4*>(&bv[4]) = *reinterpret_cast<const float4*>(&b0row[k + 4]);
            split8(bv, bhi, blo);
            fa0 = __builtin_amdgcn_mfma_f32_16x16x32_bf16(ahi, bhi, fa0, 0, 0, 0);
            fa0 = __builtin_amdgcn_mfma_f32_16x16x32_bf16(alo, bhi, fa0, 0, 0, 0);
            fa0 = __builtin_amdgcn_mfma_f32_16x16x32_bf16(ahi, blo, fa0, 0, 0, 0);
            *reinterpret_cast<float4*>(&bv[0]) = *reinterpret_cast<const float4*>(&b1row[k]);
            *reinterpret_cast<float4*>(&bv[4]) = *reinterpret_cast<const float4*>(&b1row[k + 4]);
            split8(bv, bhi, blo);
            fa1 = __builtin_amdgcn_mfma_f32_16x16x32_bf16(ahi, bhi, fa1, 0, 0, 0);
            fa1 = __builtin_amdgcn_mfma_f32_16x16x32_bf16(alo, bhi, fa1, 0, 0, 0);
            fa1 = __builtin_amdgcn_mfma_f32_16x16x32_bf16(ahi, blo, fa1, 0, 0, 0);
        }
        // D rows r=0/1 (lanes 0..15) correspond to groups 0/1
        if (l < 16) {
            const long bt0  = (long)blockIdx.x * 2;
            const int row0  = (int)(bt0 & 31) * 32 + (int)(bt0 >> 5);
            const int row1  = (int)((bt0 + 1) & 31) * 32 + (int)((bt0 + 1) >> 5);
            const int o0 = obase + l;
            const int o1 = obase + 16 + l;
            const float fb0 = fc1_b[o0];
            const float fb1 = fc1_b[o1];
            out[row0 * 256 + o0] = fa0[0] + fb0;
            out[row1 * 256 + o0] = fa0[1] + fb0;
            out[row0 * 256 + o1] = fa1[0] + fb1;
            out[row1 * 256 + o1] = fa1[1] + fb1;
        }
    }
}

extern "C" void kernel_launch(void* const* d_in, const int* in_sizes, int n_in,
                              void* d_out, int out_size, void* d_ws, size_t ws_size,
                              hipStream_t stream) {
    const float* inp   = (const float*)d_in[0];
    const float* ue_w  = (const float*)d_in[1];
    const float* ue_b  = (const float*)d_in[2];
    const float* be    = (const float*)d_in[3];
    const float* w_w   = (const float*)d_in[4];
    // d_in[5] = w_b: unused (softmax invariant to constant shift)
    const float* fc1_w = (const float*)d_in[6];
    const float* fc1_b = (const float*)d_in[7];
    float* out = (float*)d_out;

    stattn_all<<<512, 512, 0, stream>>>(inp, ue_w, ue_b, be, w_w, fc1_w, fc1_b, out);
}

// Round 4
// 98.498 us; speedup vs baseline: 1.1638x; 1.0573x over previous
//
#include <hip/hip_runtime.h>

// STAttn fused v3: B,T,N,D = 32,32,64,512; H=64; OUT=256.
// 1024 blocks (1 bt each) x 512 threads (8 waves) -> 8192 waves = 32/CU (100%).
// Waves = (nh, jh, kh): 32x32 h-tile over K=256 each; kh pair combines via LDS.
// Phase 1: k-tiled (32) cooperative LDS staging of x & ue_w as bf16 hi/lo in
//          MFMA fragment layout (chunk-major), split ONCE per element per block
//          with cheap trunc-split; 3x mfma_f32_32x32x16_bf16 per 16-k step.
// Phase 2: e = lrelu(h+bias)@w_w partial-reduced via shfl; softmax over N=64.
// Phase 3: pooling attr = sum_n a_n x_n (x re-read, L2/L3-resident).
// Phase 4: fc = attr @ fc1_w^T in plain fp32 VALU (M=1: MFMA/splits wasteful).
// No d_ws use.

typedef __attribute__((ext_vector_type(8)))  short bf16x8;
typedef __attribute__((ext_vector_type(16))) float f32x16;

// cheap fp32 -> bf16 hi (trunc) + lo (residual, trunc). Combined precision
// ~2^-16 relative: lo captures the exact fp32 residual of the truncated hi;
// only the alo*blo cross term (~2^-16) is dropped by the 3-MFMA scheme.
__device__ __forceinline__ void split8t(const float* __restrict__ v,
                                        bf16x8& h8, bf16x8& l8) {
#pragma unroll
    for (int i = 0; i < 8; ++i) {
        const unsigned u = __float_as_uint(v[i]);
        h8[i] = (short)(u >> 16);
        const float hf = __uint_as_float(u & 0xFFFF0000u);
        l8[i] = (short)(__float_as_uint(v[i] - hf) >> 16);
    }
}

__global__ __launch_bounds__(512, 8) void stattn_all(
    const float* __restrict__ inp,    // [1024][64][512]
    const float* __restrict__ ue_w,   // [64][512]
    const float* __restrict__ ue_b,   // [64]
    const float* __restrict__ be,     // [64]
    const float* __restrict__ w_w,    // [64]
    const float* __restrict__ fc1_w,  // [256][512]
    const float* __restrict__ fc1_b,  // [256]
    float* __restrict__ out)          // [1024][256]
{
    // staging: [kh][chunk][row][8] shorts, chunk-major so frag reads are
    // 32 consecutive 16B lanes (conflict-free). 8 KB each.
    __shared__ __align__(16) short xh[2][4][64][8];
    __shared__ __align__(16) short xl[2][4][64][8];
    __shared__ __align__(16) short wh[2][4][64][8];
    __shared__ __align__(16) short wl[2][4][64][8];
    __shared__ float ep_s[2][64];
    __shared__ float a_s[64];
    __shared__ __align__(16) float attr_s[512];

    const int tid = threadIdx.x;
    const int wv  = tid >> 6;
    const int l   = tid & 63;
    const int l31 = l & 31;
    const int hi5 = l >> 5;
    const int kh  = wv & 1;         // K half (0: k<256, 1: k>=256)
    const int jh  = (wv >> 1) & 1;  // hidden half
    const int nh  = wv >> 2;        // token half

    const float* __restrict__ xg = inp + (size_t)blockIdx.x * (64 * 512);

    // staging role: 4 lanes per row cover 128B contiguous (coalesced)
    const int s_row = (tid >> 2) & 63;
    const int s_sc  = tid & 3;
    const int s_w   = tid >> 8;  // waves 0-3 stage x, waves 4-7 stage ue_w
    const float* __restrict__ s_base =
        (s_w ? ue_w : xg) + s_row * 512 + s_sc * 8;

    f32x16 acc = {};

    for (int kt = 0; kt < 8; ++kt) {
        __syncthreads();  // previous tile's readers done
#pragma unroll
        for (int khs = 0; khs < 2; ++khs) {
            float av[8];
            const float* p = s_base + kt * 32 + khs * 256;
            *reinterpret_cast<float4*>(&av[0]) = *reinterpret_cast<const float4*>(p);
            *reinterpret_cast<float4*>(&av[4]) = *reinterpret_cast<const float4*>(p + 4);
            bf16x8 h8, l8;
            split8t(av, h8, l8);
            if (s_w) {
                *reinterpret_cast<bf16x8*>(&wh[khs][s_sc][s_row][0]) = h8;
                *reinterpret_cast<bf16x8*>(&wl[khs][s_sc][s_row][0]) = l8;
            } else {
                *reinterpret_cast<bf16x8*>(&xh[khs][s_sc][s_row][0]) = h8;
                *reinterpret_cast<bf16x8*>(&xl[khs][s_sc][s_row][0]) = l8;
            }
        }
        __syncthreads();
#pragma unroll
        for (int s = 0; s < 2; ++s) {
            const int c  = 2 * s + hi5;   // k-chunk: lane half picks 8-k sub
            const int ar = nh * 32 + l31;
            const int br = jh * 32 + l31;
            const bf16x8 ah = *reinterpret_cast<const bf16x8*>(&xh[kh][c][ar][0]);
            const bf16x8 al = *reinterpret_cast<const bf16x8*>(&xl[kh][c][ar][0]);
            const bf16x8 bh = *reinterpret_cast<const bf16x8*>(&wh[kh][c][br][0]);
            const bf16x8 bl = *reinterpret_cast<const bf16x8*>(&wl[kh][c][br][0]);
            acc = __builtin_amdgcn_mfma_f32_32x32x16_bf16(ah, bh, acc, 0, 0, 0);
            acc = __builtin_amdgcn_mfma_f32_32x32x16_bf16(al, bh, acc, 0, 0, 0);
            acc = __builtin_amdgcn_mfma_f32_32x32x16_bf16(ah, bl, acc, 0, 0, 0);
        }
    }

    // ---- combine kh partials (reuse staging LDS as fp32 scratch) ----
    __syncthreads();  // all staging reads done
    {
        const int tile = nh * 2 + jh;
        float* hp = (tile < 2) ? reinterpret_cast<float*>(xh)
                               : reinterpret_cast<float*>(xl);
        const int toff = (tile & 1) * 1024 + l;
        if (kh == 1) {
#pragma unroll
            for (int r = 0; r < 16; ++r) hp[toff + r * 64] = acc[r];
        }
        __syncthreads();
        if (kh == 0) {
#pragma unroll
            for (int r = 0; r < 16; ++r) acc[r] += hp[toff + r * 64];
            // ---- phase 2: bias + lrelu + dot w_w (w_b shift dropped) ----
            // C/D layout: col j = l&31, row n = (r&3) + 8*(r>>2) + 4*(l>>5)
            const int j = jh * 32 + l31;
            const float bias = ue_b[j] + be[j];
            const float ww   = w_w[j];
#pragma unroll
            for (int r = 0; r < 16; ++r) {
                float hv = acc[r] + bias;
                hv = hv > 0.f ? hv : 0.2f * hv;
                float p = hv * ww;
                p += __shfl_xor(p, 1);
                p += __shfl_xor(p, 2);
                p += __shfl_xor(p, 4);
                p += __shfl_xor(p, 8);
                p += __shfl_xor(p, 16);
                if (l31 == 0) {
                    const int nr = (r & 3) + 8 * (r >> 2) + 4 * hi5;
                    ep_s[jh][nh * 32 + nr] = p;
                }
            }
        }
    }
    __syncthreads();

    // ---- softmax over 64 tokens (all waves compute; wave 0 writes) ----
    {
        const float v = ep_s[0][l] + ep_s[1][l];
        float mx = v;
#pragma unroll
        for (int off = 32; off >= 1; off >>= 1) mx = fmaxf(mx, __shfl_xor(mx, off));
        const float ex = expf(v - mx);
        float sm = ex;
#pragma unroll
        for (int off = 32; off >= 1; off >>= 1) sm += __shfl_xor(sm, off);
        if (wv == 0) a_s[l] = ex / sm;
    }
    __syncthreads();

    // ---- phase 3: pooling, thread d = tid (coalesced 2KB row reads) ----
    {
        const int d = tid;
        float s = 0.f;
#pragma unroll 8
        for (int n = 0; n < 64; ++n) s = fmaf(a_s[n], xg[n * 512 + d], s);
        attr_s[d] = s;
    }
    __syncthreads();

    // ---- phase 4: fc, fp32 VALU; 2 threads per output o ----
    {
        const int o  = tid >> 1;
        const int ks = tid & 1;
        const float* __restrict__ wrow = fc1_w + o * 512 + ks * 256;
        const float* __restrict__ ap   = attr_s + ks * 256;
        float s0 = 0.f, s1 = 0.f, s2 = 0.f, s3 = 0.f;
#pragma unroll 8
        for (int i = 0; i < 64; ++i) {
            const float4 w4 = *reinterpret_cast<const float4*>(&wrow[i * 4]);
            const float4 a4 = *reinterpret_cast<const float4*>(&ap[i * 4]);
            s0 = fmaf(a4.x, w4.x, s0);
            s1 = fmaf(a4.y, w4.y, s1);
            s2 = fmaf(a4.z, w4.z, s2);
            s3 = fmaf(a4.w, w4.w, s3);
        }
        float p = (s0 + s1) + (s2 + s3);
        p += __shfl_xor(p, 1);
        if (ks == 0) {
            const int bt  = blockIdx.x;
            const int row = (bt & 31) * 32 + (bt >> 5);  // t*B + b
            out[row * 256 + o] = p + fc1_b[o];
        }
    }
}

extern "C" void kernel_launch(void* const* d_in, const int* in_sizes, int n_in,
                              void* d_out, int out_size, void* d_ws, size_t ws_size,
                              hipStream_t stream) {
    const float* inp   = (const float*)d_in[0];
    const float* ue_w  = (const float*)d_in[1];
    const float* ue_b  = (const float*)d_in[2];
    const float* be    = (const float*)d_in[3];
    const float* w_w   = (const float*)d_in[4];
    // d_in[5] = w_b: unused (softmax invariant to constant shift)
    const float* fc1_w = (const float*)d_in[6];
    const float* fc1_b = (const float*)d_in[7];
    float* out = (float*)d_out;

    stattn_all<<<1024, 512, 0, stream>>>(inp, ue_w, ue_b, be, w_w, fc1_w, fc1_b, out);
}